// Round 4
// baseline (15395.178 us; speedup 1.0000x reference)
//
#include <hip/hip_runtime.h>
#include <math.h>

#define NEGF   (-1e30f)
#define FINTH  (-5e29f)
#define VSZ    32000
#define SEQL   34    // T+1, T = 33
#define NT     500   // 32000/64 column tiles
#define GRID   256   // == CU count; one block per CU -> co-residency guaranteed

struct Params {
  const int* source;
  const float* emb_src; const float* emb_tgt;
  const float* eWih; const float* eWhh; const float* ebih; const float* ebhh;
  const float* dWih; const float* dWhh; const float* dbih; const float* dbhh;
  const float* Wout; const float* bout;
  int* out;
  float* hA; float* hB;
  float* pmax; float* psum; float* cv;
  int* ci;
  float* act_ll; float* best_ll;
  int* wordb; int* hsrc; int* seqs0; int* seqs1; int* bseq;
  int* bar_flags;   // [GRID]
  int* bar_master;  // [1]
};

// ---- software grid barrier (normal launch; all 256 blocks co-resident).
// Generation-counted, exact-equality, so 0xAA poison needs no init.
__device__ __forceinline__ void gbar(int* flags, int* master, int gen,
                                     int blk, int tid)
{
  __syncthreads();
  __threadfence();                       // drain this block's writes device-wide
  if (tid == 0) atomicExch(&flags[blk], gen);
  if (blk == 0) {
    // 256 threads each own one block's flag
    while (atomicAdd(&flags[tid], 0) != gen) __builtin_amdgcn_s_sleep(1);
    __syncthreads();
    if (tid == 0) atomicExch(master, gen);
  }
  if (tid == 0) {
    while (atomicAdd(master, 0) != gen) __builtin_amdgcn_s_sleep(1);
  }
  __syncthreads();
  __threadfence();                       // acquire: invalidate L1 before reads
}

__device__ __forceinline__ bool cand_gt(float av, int ai, float bv, int bi) {
  return (av > bv) || (av == bv && ai < bi);
}

#define INS5(xx, ii)                                                           \
  if (cand_gt(xx, ii, tv4, ti4)) {                                             \
    tv4 = xx; ti4 = ii;                                                        \
    if (cand_gt(tv4, ti4, tv3, ti3)) { float tf = tv3; int tj = ti3; tv3 = tv4; ti3 = ti4; tv4 = tf; ti4 = tj; \
      if (cand_gt(tv3, ti3, tv2, ti2)) { tf = tv2; tj = ti2; tv2 = tv3; ti2 = ti3; tv3 = tf; ti3 = tj; \
        if (cand_gt(tv2, ti2, tv1, ti1)) { tf = tv1; tj = ti1; tv1 = tv2; ti1 = ti2; tv2 = tf; ti2 = tj; \
          if (cand_gt(tv1, ti1, tv0, ti0)) { tf = tv0; tj = ti0; tv0 = tv1; ti0 = ti1; tv1 = tf; ti1 = tj; } } } } }

// ---- fused gates GEMM + GRU update. Block handles 4 hidden dims for all M
// rows. R=1 -> M=32 (encoder), R=5 -> M=160 (decoder). Blocks 0..127 active.
template<int R>
__device__ void gru_step(const float* __restrict__ emb, const int* __restrict__ tokp,
                         int tokstride, const float* __restrict__ hc,
                         const int* __restrict__ hsrc,
                         const float* __restrict__ Wih, const float* __restrict__ Whh,
                         const float* __restrict__ bih, const float* __restrict__ bhh,
                         float* __restrict__ hn, float* smem, int blk, int tid)
{
  const int M = 32 * R;
  float* xs = smem;                 // [M][36]
  float* hs = smem + M * 36;        // [M][36]
  float* Ws = smem + 2 * M * 36;    // [24][36]
  const int j0 = blk * 4;

  const int mbs = tid >> 3, f4 = (tid & 7) * 4;
  const float* xrow[R];
  const float* hrow[R];
  #pragma unroll
  for (int r = 0; r < R; r++) {
    int m = mbs + 32 * r;
    xrow[r] = emb + (long)tokp[m * tokstride] * 512;
    hrow[r] = hc + (long)(hsrc ? hsrc[m] : m) * 512;
  }
  const float* wrow = Wih;
  if (tid < 192) {
    int u = tid >> 3;
    int uu = (u < 12) ? u : u - 12;
    int g = uu >> 2, d = uu & 3;
    wrow = ((u < 12) ? Wih : Whh) + (long)(g * 512 + j0 + d) * 512;
  }
  float acc[R][3];
  #pragma unroll
  for (int r = 0; r < R; r++) { acc[r][0] = 0.f; acc[r][1] = 0.f; acc[r][2] = 0.f; }

  const int ug = tid >> 5;   // 0..7
  const int u0 = ug * 3;     // units u0..u0+2 (all x-side or all h-side)
  const int mb = tid & 31;
  float* As = (u0 < 12) ? xs : hs;

  for (int k0 = 0; k0 < 512; k0 += 32) {
    __syncthreads();
    #pragma unroll
    for (int r = 0; r < R; r++) {
      int m = mbs + 32 * r;
      *(float4*)&xs[m * 36 + f4] = *(const float4*)(xrow[r] + k0 + f4);
      *(float4*)&hs[m * 36 + f4] = *(const float4*)(hrow[r] + k0 + f4);
    }
    if (tid < 192)
      *(float4*)&Ws[(tid >> 3) * 36 + f4] = *(const float4*)(wrow + k0 + f4);
    __syncthreads();
    #pragma unroll
    for (int k = 0; k < 32; k += 4) {
      float4 w0 = *(const float4*)&Ws[(u0 + 0) * 36 + k];
      float4 w1 = *(const float4*)&Ws[(u0 + 1) * 36 + k];
      float4 w2 = *(const float4*)&Ws[(u0 + 2) * 36 + k];
      #pragma unroll
      for (int r = 0; r < R; r++) {
        float4 a = *(const float4*)&As[(mb + 32 * r) * 36 + k];
        acc[r][0] += a.x*w0.x + a.y*w0.y + a.z*w0.z + a.w*w0.w;
        acc[r][1] += a.x*w1.x + a.y*w1.y + a.z*w1.z + a.w*w1.w;
        acc[r][2] += a.x*w2.x + a.y*w2.y + a.z*w2.z + a.w*w2.w;
      }
    }
  }
  __syncthreads();
  float* gacc = smem;   // [M][25], overlays xs
  #pragma unroll
  for (int r = 0; r < R; r++) {
    int m = mb + 32 * r;
    gacc[m * 25 + u0 + 0] = acc[r][0];
    gacc[m * 25 + u0 + 1] = acc[r][1];
    gacc[m * 25 + u0 + 2] = acc[r][2];
  }
  __syncthreads();
  if (tid < M) {
    int m = tid;
    const float* hold = hc + (long)(hsrc ? hsrc[m] : m) * 512;
    #pragma unroll
    for (int d = 0; d < 4; d++) {
      int j = j0 + d;
      float ir  = gacc[m*25 + d]      + bih[j];
      float iz  = gacc[m*25 + 4 + d]  + bih[512 + j];
      float in_ = gacc[m*25 + 8 + d]  + bih[1024 + j];
      float hr  = gacc[m*25 + 12 + d] + bhh[j];
      float hz  = gacc[m*25 + 16 + d] + bhh[512 + j];
      float hnv = gacc[m*25 + 20 + d] + bhh[1024 + j];
      float rr = 1.f / (1.f + expf(-(ir + hr)));
      float zz = 1.f / (1.f + expf(-(iz + hz)));
      float nn = tanhf(in_ + rr * hnv);
      hn[(long)m * 512 + j] = (1.f - zz) * nn + zz * hold[j];
    }
  }
  __syncthreads();
}

// ---- logits tiles (64 cols each, grid-stride) + fused per-row softmax
// partials + per-row top5. Never materializes the logits tensor.
__device__ void logits_phase(const float* __restrict__ h1, const float* __restrict__ Wout,
                             const float* __restrict__ bout,
                             float* __restrict__ pmax, float* __restrict__ psum,
                             float* __restrict__ cv, int* __restrict__ ci,
                             float* smem, int blk, int tid)
{
  for (int tile = blk; tile < NT; tile += GRID) {
    const int v0 = tile * 64;
    float* A  = smem;             // [160][36]
    float* Bw = smem + 160 * 36;  // [64][36]
    const int vg = tid & 15, mg = tid >> 4;
    float acc[10][4];
    #pragma unroll
    for (int p = 0; p < 10; p++)
      #pragma unroll
      for (int i = 0; i < 4; i++) acc[p][i] = 0.f;

    for (int k0 = 0; k0 < 512; k0 += 32) {
      __syncthreads();
      for (int idx = tid; idx < 160 * 8; idx += 256) {
        int m = idx >> 3, f = idx & 7;
        *(float4*)&A[m * 36 + f * 4] = *(const float4*)(h1 + (long)m * 512 + k0 + f * 4);
      }
      for (int idx = tid; idx < 512; idx += 256) {
        int k = idx >> 4, f = idx & 15;
        float4 w = *(const float4*)(Wout + (long)(k0 + k) * VSZ + v0 + f * 4);
        Bw[(f * 4 + 0) * 36 + k] = w.x;
        Bw[(f * 4 + 1) * 36 + k] = w.y;
        Bw[(f * 4 + 2) * 36 + k] = w.z;
        Bw[(f * 4 + 3) * 36 + k] = w.w;
      }
      __syncthreads();
      #pragma unroll
      for (int k = 0; k < 32; k += 4) {
        float4 w[4];
        #pragma unroll
        for (int i = 0; i < 4; i++) w[i] = *(const float4*)&Bw[(vg * 4 + i) * 36 + k];
        #pragma unroll
        for (int p = 0; p < 10; p++) {
          float4 a = *(const float4*)&A[(mg + 16 * p) * 36 + k];
          #pragma unroll
          for (int i = 0; i < 4; i++)
            acc[p][i] += a.x*w[i].x + a.y*w[i].y + a.z*w[i].z + a.w*w[i].w;
        }
      }
    }
    // epilogue: dump tile (with bias) to LDS, then per-row stats+top5
    __syncthreads();
    float* tile_s = smem;   // [160][67] (odd stride -> conflict-free row scans)
    float4 bo = *(const float4*)&bout[v0 + vg * 4];
    #pragma unroll
    for (int p = 0; p < 10; p++) {
      int m = mg + 16 * p;
      tile_s[m * 67 + vg * 4 + 0] = acc[p][0] + bo.x;
      tile_s[m * 67 + vg * 4 + 1] = acc[p][1] + bo.y;
      tile_s[m * 67 + vg * 4 + 2] = acc[p][2] + bo.z;
      tile_s[m * 67 + vg * 4 + 3] = acc[p][3] + bo.w;
    }
    __syncthreads();
    if (tid < 160) {
      const float* tr = &tile_s[tid * 67];
      float mx = tr[0];
      for (int c = 1; c < 64; c++) mx = fmaxf(mx, tr[c]);
      float s = 0.f;
      float tv0=-3.4e38f, tv1=-3.4e38f, tv2=-3.4e38f, tv3=-3.4e38f, tv4=-3.4e38f;
      int ti0=0x7fffffff, ti1=0x7fffffff, ti2=0x7fffffff, ti3=0x7fffffff, ti4=0x7fffffff;
      for (int c = 0; c < 64; c++) {
        float x = tr[c];
        s += expf(x - mx);
        INS5(x, v0 + c);
      }
      long base = (long)tid * NT + tile;
      pmax[base] = mx;
      psum[base] = s;
      float* cvp = cv + base * 5;
      int*   cip = ci + base * 5;
      cvp[0]=tv0; cvp[1]=tv1; cvp[2]=tv2; cvp[3]=tv3; cvp[4]=tv4;
      cip[0]=ti0; cip[1]=ti1; cip[2]=ti2; cip[3]=ti3; cip[4]=ti4;
    }
    __syncthreads();
  }
}

// ---- per-sentence reduce: lse combine, candidate merge, bookkeeping. Blocks 0..31.
__device__ void reduce_phase(const Params& p, int t, float* smem, int b, int tid)
{
  float* s_lse = smem;                      // [5]
  float* s_red = smem + 8;                  // [8]
  float* sv    = smem + 16;                 // [256*5]
  int*   si    = (int*)(smem + 16 + 1280);  // [256*5]
  int*   lsq   = (int*)(smem + 16 + 2560);  // [5][SEQL]
  const int K = (t == 0) ? 1 : 5;

  // 1) lse per beam row (combine NT partial (max,sum) pairs)
  for (int k = 0; k < K; k++) {
    int row = b * 5 + k;
    float m = -3.0e38f, s = 0.f;
    for (int i = tid; i < NT; i += 256) {
      float pm = p.pmax[(long)row * NT + i];
      float ps = p.psum[(long)row * NT + i];
      float nm = fmaxf(m, pm);
      s = s * expf(m - nm) + ps * expf(pm - nm);
      m = nm;
    }
    for (int mask = 1; mask < 64; mask <<= 1) {
      float om = __shfl_xor(m, mask, 64);
      float os = __shfl_xor(s, mask, 64);
      float nm = fmaxf(m, om);
      s = s * expf(m - nm) + os * expf(om - nm);
      m = nm;
    }
    if ((tid & 63) == 0) { s_red[(tid >> 6) * 2] = m; s_red[(tid >> 6) * 2 + 1] = s; }
    __syncthreads();
    if (tid == 0) {
      float M2 = s_red[0], S2 = s_red[1];
      for (int w = 1; w < 4; w++) {
        float om = s_red[w * 2], os = s_red[w * 2 + 1];
        float nm = fmaxf(M2, om);
        S2 = S2 * expf(M2 - nm) + os * expf(om - nm);
        M2 = nm;
      }
      s_lse[k] = M2 + logf(S2);
    }
    __syncthreads();
  }

  // 2) merge candidates: adj = act + (logit - lse), idx = k*V + v
  float tv0=-3.4e38f, tv1=-3.4e38f, tv2=-3.4e38f, tv3=-3.4e38f, tv4=-3.4e38f;
  int ti0=0x7fffffff, ti1=0x7fffffff, ti2=0x7fffffff, ti3=0x7fffffff, ti4=0x7fffffff;
  for (int k = 0; k < K; k++) {
    int row = b * 5 + k;
    float ak = (t == 0) ? 0.f : p.act_ll[row];
    float lk = s_lse[k];
    int base = (t == 0) ? 0 : k * VSZ;
    const float* cvp = p.cv + (long)row * NT * 5;
    const int*   cip = p.ci + (long)row * NT * 5;
    for (int c = tid; c < NT * 5; c += 256) {
      float adj = ak + (cvp[c] - lk);
      int gidx = base + cip[c];
      INS5(adj, gidx);
    }
  }
  sv[tid*5+0]=tv0; si[tid*5+0]=ti0;
  sv[tid*5+1]=tv1; si[tid*5+1]=ti1;
  sv[tid*5+2]=tv2; si[tid*5+2]=ti2;
  sv[tid*5+3]=tv3; si[tid*5+3]=ti3;
  sv[tid*5+4]=tv4; si[tid*5+4]=ti4;
  __syncthreads();
  for (int str = 128; str >= 1; str >>= 1) {
    if (tid < str) {
      float* av = &sv[tid * 5];         int* ai = &si[tid * 5];
      float* bv = &sv[(tid + str) * 5]; int* bi = &si[(tid + str) * 5];
      float o0[5]; int o1[5];
      int i = 0, j = 0;
      #pragma unroll
      for (int o = 0; o < 5; o++) {
        float avv = av[i]; int aii = ai[i];
        float bvv = bv[j]; int bii = bi[j];
        bool ta = cand_gt(avv, aii, bvv, bii);
        o0[o] = ta ? avv : bvv; o1[o] = ta ? aii : bii;
        i += ta ? 1 : 0; j += ta ? 0 : 1;
      }
      #pragma unroll
      for (int o = 0; o < 5; o++) { av[o] = o0[o]; ai[o] = o1[o]; }
    }
    __syncthreads();
  }
  // all-beams-dead: reference picks flat indices 0..4 (all values -1e30 exactly)
  if (tid == 0 && sv[0] <= FINTH) {
    #pragma unroll
    for (int q = 0; q < 5; q++) { sv[q] = NEGF; si[q] = q; }
  }
  __syncthreads();

  int* sold = (t & 1) ? p.seqs0 : p.seqs1;
  int* snew = (t & 1) ? p.seqs1 : p.seqs0;

  if (t == 0) {
    if (tid < SEQL) {
      #pragma unroll
      for (int j = 0; j < 5; j++) {
        int w = si[j];
        snew[(b * 5 + j) * SEQL + tid] = (tid == 0) ? 0 : ((tid == 1) ? w : 2);
      }
      p.bseq[b * SEQL + tid] = 2;
    }
    if (tid < 5) {
      p.act_ll[b * 5 + tid] = sv[tid];
      p.wordb[b * 5 + tid] = si[tid];
      p.hsrc[b * 5 + tid] = b * 5 + tid;
    }
    if (tid == 0) p.best_ll[b] = NEGF;
  } else {
    float v[5]; int pr[5], wd[5];
    #pragma unroll
    for (int j = 0; j < 5; j++) {
      v[j] = sv[j];
      int id = si[j];
      pr[j] = id / VSZ;
      wd[j] = id - pr[j] * VSZ;
    }
    if (tid < SEQL) {
      #pragma unroll
      for (int j = 0; j < 5; j++) {
        int x = (tid == t + 1) ? wd[j] : sold[(b * 5 + pr[j]) * SEQL + tid];
        lsq[j * SEQL + tid] = x;
        snew[(b * 5 + j) * SEQL + tid] = x;
      }
    }
    float cll[5];
    #pragma unroll
    for (int j = 0; j < 5; j++) {
      bool fin = v[j] > FINTH;
      bool eos = (wd[j] == 1) && fin;
      cll[j] = eos ? v[j] / (float)(t + 2) : NEGF;
    }
    int jb = 0; float cb = cll[0];
    #pragma unroll
    for (int j = 1; j < 5; j++) if (cll[j] > cb) { cb = cll[j]; jb = j; }
    if (tid == 0) {
      float bl = p.best_ll[b];
      s_red[0] = (cb > bl) ? 1.f : 0.f;
      if (cb > bl) p.best_ll[b] = cb;
    }
    __syncthreads();
    bool improve = (s_red[0] != 0.f);
    if (improve && tid < SEQL) p.bseq[b * SEQL + tid] = lsq[jb * SEQL + tid];
    if (tid < 5) {
      bool fin = v[tid] > FINTH;
      bool eos = (wd[tid] == 1) && fin;
      p.act_ll[b * 5 + tid] = (fin && !eos) ? v[tid] : NEGF;
      p.wordb[b * 5 + tid] = wd[tid];
      p.hsrc[b * 5 + tid] = b * 5 + pr[tid];
    }
    if (t == 32) {
      __syncthreads();
      bool have = p.best_ll[b] > FINTH;
      float ab = p.act_ll[b * 5]; int jb2 = 0;
      for (int j = 1; j < 5; j++) {
        float aj = p.act_ll[b * 5 + j];
        if (aj > ab) { ab = aj; jb2 = j; }
      }
      if (tid < SEQL)
        p.out[b * SEQL + tid] = have ? p.bseq[b * SEQL + tid]
                                     : snew[(b * 5 + jb2) * SEQL + tid];
    }
  }
  __syncthreads();
}

__global__ __launch_bounds__(256) void mega(Params p)
{
  __shared__ __align__(16) float smem[12384];   // 49.5 KB
  const int blk = blockIdx.x;
  const int tid = threadIdx.x;
  int gen = 0;

  // init (ws is poisoned 0xAA before every call)
  if (blk < 64) {
    p.hA[blk * 256 + tid] = 0.f;
  } else if (blk == 64 && tid < 160) {
    p.wordb[tid] = 0;          // SOS
    p.hsrc[tid] = tid / 5;     // beam -> encoder sentence row
  }
  gbar(p.bar_flags, p.bar_master, ++gen, blk, tid);

  float* hc = p.hA;
  float* hn = p.hB;
  // encoder: 32 GRU steps, M = 32
  for (int s = 0; s < 32; s++) {
    if (blk < 128)
      gru_step<1>(p.emb_src, p.source + s, 32, hc, nullptr,
                  p.eWih, p.eWhh, p.ebih, p.ebhh, hn, smem, blk, tid);
    gbar(p.bar_flags, p.bar_master, ++gen, blk, tid);
    float* tmp = hc; hc = hn; hn = tmp;
  }
  // decode: t=0 initial advance, t=1..32 beam steps
  for (int t = 0; t <= 32; t++) {
    if (blk < 128)
      gru_step<5>(p.emb_tgt, p.wordb, 1, hc, p.hsrc,
                  p.dWih, p.dWhh, p.dbih, p.dbhh, hn, smem, blk, tid);
    gbar(p.bar_flags, p.bar_master, ++gen, blk, tid);
    logits_phase(hn, p.Wout, p.bout, p.pmax, p.psum, p.cv, p.ci, smem, blk, tid);
    gbar(p.bar_flags, p.bar_master, ++gen, blk, tid);
    if (blk < 32)
      reduce_phase(p, t, smem, blk, tid);
    gbar(p.bar_flags, p.bar_master, ++gen, blk, tid);
    float* tmp = hc; hc = hn; hn = tmp;
  }
}

extern "C" void kernel_launch(void* const* d_in, const int* in_sizes, int n_in,
                              void* d_out, int out_size, void* d_ws, size_t ws_size,
                              hipStream_t stream)
{
  Params p;
  p.source  = (const int*)d_in[0];
  p.emb_src = (const float*)d_in[1];
  p.emb_tgt = (const float*)d_in[2];
  p.eWih = (const float*)d_in[3];
  p.eWhh = (const float*)d_in[4];
  p.ebih = (const float*)d_in[5];
  p.ebhh = (const float*)d_in[6];
  p.dWih = (const float*)d_in[7];
  p.dWhh = (const float*)d_in[8];
  p.dbih = (const float*)d_in[9];
  p.dbhh = (const float*)d_in[10];
  p.Wout = (const float*)d_in[11];
  p.bout = (const float*)d_in[12];
  p.out  = (int*)d_out;

  char* ws = (char*)d_ws;
  size_t off = 0;
  auto alloc = [&](size_t bytes) {
    void* q = ws + off;
    off = (off + bytes + 255) & ~(size_t)255;
    return q;
  };
  p.hA      = (float*)alloc(160 * 512 * 4);
  p.hB      = (float*)alloc(160 * 512 * 4);
  p.pmax    = (float*)alloc((size_t)160 * NT * 4);
  p.psum    = (float*)alloc((size_t)160 * NT * 4);
  p.cv      = (float*)alloc((size_t)160 * NT * 5 * 4);
  p.ci      = (int*)  alloc((size_t)160 * NT * 5 * 4);
  p.act_ll  = (float*)alloc(160 * 4);
  p.best_ll = (float*)alloc(32 * 4);
  p.wordb   = (int*)  alloc(160 * 4);
  p.hsrc    = (int*)  alloc(160 * 4);
  p.seqs0   = (int*)  alloc(160 * SEQL * 4);
  p.seqs1   = (int*)  alloc(160 * SEQL * 4);
  p.bseq    = (int*)  alloc(32 * SEQL * 4);
  p.bar_flags  = (int*)alloc(GRID * 4);
  p.bar_master = (int*)alloc(4);

  mega<<<GRID, 256, 0, stream>>>(p);
}